// Round 10
// baseline (422.475 us; speedup 1.0000x reference)
//
#include <hip/hip_runtime.h>
#include <hip/hip_bf16.h>

#define NN 100000
#define DD 128

// Bucketed CSR build: 512 nodes per bucket
#define NPB 512
#define NB 196                     // ceil(100000/512)
#define CAPB 12288                 // pairs/bucket (mean 8192, huge slack)
#define PA_BLOCKS 196              // measured optimum (784 -> 3.6x write amp r7;
                                   // counting sort -> 16x amp r8)
#define GBLK 782                   // ceil(NN/128)

typedef unsigned short ushort_t;
typedef unsigned int uint_t;
typedef __attribute__((ext_vector_type(8))) short bf16x8;
typedef __attribute__((ext_vector_type(4))) float f32x4;

__device__ __forceinline__ ushort_t f2bf(float f) {
    uint_t u = __builtin_bit_cast(uint_t, f);
    u += 0x7FFFu + ((u >> 16) & 1u);          // RNE
    return (ushort_t)(u >> 16);
}
__device__ __forceinline__ uint_t pack2bf(float a, float b) {
    return (uint_t)f2bf(a) | ((uint_t)f2bf(b) << 16);
}
__device__ __forceinline__ float bflo(uint_t v) {
    return __builtin_bit_cast(float, v << 16);
}
__device__ __forceinline__ float bfhi(uint_t v) {
    return __builtin_bit_cast(float, v & 0xFFFF0000u);
}

// async global->LDS, 16 B per lane (dest = wave-uniform base + lane*16).
__device__ __forceinline__ void gload16(const ushort_t* g, ushort_t* l) {
    __builtin_amdgcn_global_load_lds(
        (const __attribute__((address_space(1))) void*)g,
        (__attribute__((address_space(3))) void*)l,
        16, 0, 0);
}

// ---------------------------------------------------------------------------
// prep: weight transposes (blocks 0..319) + bcnt zeroing (320..321) +
// zero pad-row NN of h1/h2 (block 322).
// ---------------------------------------------------------------------------
#define PREP_W_BLOCKS 320
#define PREP_Z_BLOCKS 3
__global__ __launch_bounds__(256) void prep(
    const float* __restrict__ w_proj,
    const float* __restrict__ w_self1, const float* __restrict__ w_neigh1,
    const float* __restrict__ w_self2, const float* __restrict__ w_neigh2,
    ushort_t* __restrict__ wtp, ushort_t* __restrict__ wt1,
    ushort_t* __restrict__ wt2, int* __restrict__ bcnt,
    ushort_t* __restrict__ h1pad, ushort_t* __restrict__ h2pad)
{
    const int bid = blockIdx.x;
    const int tid = threadIdx.x;
    if (bid < PREP_W_BLOCKS) {
        int which = bid >> 6;                 // 0..4
        int t = (bid & 63) * 256 + tid;       // 0..16383
        int n = t >> 7, k = t & 127;
        float v;
        ushort_t* d;
        switch (which) {
            case 0: v = w_proj  [(size_t)k * 128 + n]; d = wtp + (size_t)n * 128 + k;       break;
            case 1: v = w_self1 [(size_t)k * 128 + n]; d = wt1 + (size_t)n * 256 + k;       break;
            case 2: v = w_neigh1[(size_t)k * 128 + n]; d = wt1 + (size_t)n * 256 + 128 + k; break;
            case 3: v = w_self2 [(size_t)k * 128 + n]; d = wt2 + (size_t)n * 256 + k;       break;
            default:v = w_neigh2[(size_t)k * 128 + n]; d = wt2 + (size_t)n * 256 + 128 + k; break;
        }
        *d = f2bf(v);
    } else if (bid < PREP_W_BLOCKS + 2) {
        int i = (bid - PREP_W_BLOCKS) * 256 + tid;
        if (i < 2 * NB) bcnt[i] = 0;
    } else {
        uint_t* p1 = (uint_t*)h1pad;
        uint_t* p2 = (uint_t*)h2pad;
        if (tid < 64) p1[tid] = 0;
        else if (tid < 128) p2[tid - 64] = 0;
    }
}

// ---------------------------------------------------------------------------
// gemm0 (layer 0, CVT): h1 = relu(feat @ Wp + b). fp32 A reg-converted,
// W via gload_lds, single-buffer (r6-verified path).
// ---------------------------------------------------------------------------
__global__ __launch_bounds__(256, 4) void gemm0(
    const float* __restrict__ feat, const ushort_t* __restrict__ W,
    const float* __restrict__ bias, ushort_t* __restrict__ outp)
{
    __shared__ char smem[32768];
    ushort_t* At = (ushort_t*)smem;             // 128*32*2 = 8192 B
    ushort_t* Wt = (ushort_t*)(smem + 8192);    // 8192 B
    ushort_t* Ot = (ushort_t*)smem;             // epilogue: full 32 KB

    const int tid  = threadIdx.x;
    const int lane = tid & 63;
    const int wav  = tid >> 6;
    const int row0 = blockIdx.x * 128;
    const int m0   = (wav & 1) * 64;
    const int n0   = (wav >> 1) * 64;

    f32x4 acc[4][4];
#pragma unroll
    for (int i = 0; i < 4; ++i)
#pragma unroll
        for (int j = 0; j < 4; ++j) acc[i][j] = (f32x4){0.f, 0.f, 0.f, 0.f};

    const int cl = lane & 15;
    const int q  = lane >> 4;

#pragma unroll 1
    for (int ch = 0; ch < 4; ++ch) {
        const int kA = ch * 32;

        if (ch) __syncthreads();
#pragma unroll
        for (int j = 0; j < 2; ++j) {
            int cb = (j * 4 + wav) * 64;
            int c  = cb + lane;
            int r  = c >> 2, k2 = c & 3;
            gload16(W + (size_t)r * 128 + kA + k2 * 8, Wt + cb * 8);
        }
        uint4 av[2];
#pragma unroll
        for (int j = 0; j < 2; ++j) {
            int g = tid + 256 * j;
            int r = g >> 2;
            int c = (g & 3) * 8;
            int grow = row0 + r;
            if (grow >= NN) grow = NN - 1;
            float4 f0 = *(const float4*)(feat + (size_t)grow * DD + kA + c);
            float4 f1 = *(const float4*)(feat + (size_t)grow * DD + kA + c + 4);
            av[j].x = pack2bf(f0.x, f0.y);
            av[j].y = pack2bf(f0.z, f0.w);
            av[j].z = pack2bf(f1.x, f1.y);
            av[j].w = pack2bf(f1.z, f1.w);
        }
#pragma unroll
        for (int j = 0; j < 2; ++j) {
            int g = tid + 256 * j;
            int r = g >> 2;
            int c = (g & 3) * 8;
            *(uint4*)(&At[r * 32 + c]) = av[j];
        }
        __syncthreads();

        bf16x8 af[4], bfr[4];
#pragma unroll
        for (int i = 0; i < 4; ++i)
            af[i] = *(const bf16x8*)(&At[(m0 + i * 16 + cl) * 32 + q * 8]);
#pragma unroll
        for (int j = 0; j < 4; ++j)
            bfr[j] = *(const bf16x8*)(&Wt[(n0 + j * 16 + cl) * 32 + q * 8]);
#pragma unroll
        for (int i = 0; i < 4; ++i)
#pragma unroll
            for (int j = 0; j < 4; ++j)
                acc[i][j] = __builtin_amdgcn_mfma_f32_16x16x32_bf16(
                    af[i], bfr[j], acc[i][j], 0, 0, 0);
    }

    // Epilogue. C/D layout: col=lane&15, row=(lane>>4)*4+reg  [m89/m91]
    __syncthreads();
#pragma unroll
    for (int j = 0; j < 4; ++j) {
        int c = n0 + j * 16 + cl;
        float bv = bias[c];
#pragma unroll
        for (int i = 0; i < 4; ++i) {
#pragma unroll
            for (int reg = 0; reg < 4; ++reg) {
                int r = m0 + i * 16 + 4 * q + reg;
                float v = acc[i][j][reg] + bv;
                v = fmaxf(v, 0.f);
                Ot[r * 128 + c] = f2bf(v);
            }
        }
    }
    __syncthreads();
    int rows = NN - row0; if (rows > 128) rows = 128;
    for (int t = tid; t < rows * 16; t += 256) {
        int r = t >> 4, c8 = (t & 15) * 8;
        *(uint4*)(outp + (size_t)(row0 + r) * DD + c8) =
            *(const uint4*)(&Ot[r * 128 + c8]);
    }
}

// ---------------------------------------------------------------------------
// partA2: bin BOTH edge lists into 512-node buckets (r6 config, unchanged).
// ---------------------------------------------------------------------------
__global__ __launch_bounds__(256) void partA2(
    const int* __restrict__ e0s, const int* __restrict__ e0d, int E0,
    const int* __restrict__ e1s, const int* __restrict__ e1d, int E1,
    int* __restrict__ bcnt, uint_t* __restrict__ pairs)
{
    __shared__ int hist[NB];
    __shared__ int base[NB];
    const int tid  = threadIdx.x;
    const int half = blockIdx.x >= PA_BLOCKS;
    const int* __restrict__ src = half ? e1s : e0s;
    const int* __restrict__ dst = half ? e1d : e0d;
    const int E = half ? E1 : E0;
    int* bc = bcnt + half * NB;
    uint_t* pp = pairs + (size_t)half * NB * CAPB;
    const int blk = blockIdx.x - half * PA_BLOCKS;
    const int chunk = (E + PA_BLOCKS - 1) / PA_BLOCKS;
    const int ea = blk * chunk;
    int eb = ea + chunk; if (eb > E) eb = E;

    for (int b = tid; b < NB; b += 256) hist[b] = 0;
    __syncthreads();
    for (int e = ea + tid; e < eb; e += 256)
        atomicAdd(&hist[dst[e] >> 9], 1);
    __syncthreads();
    for (int b = tid; b < NB; b += 256) {
        base[b] = atomicAdd(&bc[b], hist[b]);
        hist[b] = 0;
    }
    __syncthreads();
    for (int e = ea + tid; e < eb; e += 256) {
        int d = dst[e];
        int b = d >> 9;
        int off = atomicAdd(&hist[b], 1);
        int p = base[b] + off;
        if (p < CAPB)
            pp[(size_t)b * CAPB + p] =
                ((uint_t)(d & (NPB - 1)) << 17) | (uint_t)src[e];
    }
}

// ---------------------------------------------------------------------------
// partB: one block per bucket; sort pairs by local dst in LDS (unchanged).
// ---------------------------------------------------------------------------
__global__ __launch_bounds__(256, 2) void partB(
    uint_t* __restrict__ pairs, const int* __restrict__ bcnt,
    int* __restrict__ counts, int* __restrict__ offs)
{
    __shared__ int cnt[NPB];
    __shared__ int loff[NPB];
    __shared__ int ssc[256];
    __shared__ int image[CAPB];

    const int tid  = threadIdx.x;
    const int half = blockIdx.x >= NB;
    const int b    = blockIdx.x - half * NB;
    const int n0   = b << 9;
    int nb = NN - n0; if (nb > NPB) nb = NPB;
    int tot = bcnt[half * NB + b]; if (tot > CAPB) tot = CAPB;
    uint_t* pb = pairs + (size_t)(half * NB + b) * CAPB;
    const int gbase = (half * NB + b) * CAPB;
    int* cnts  = counts + (size_t)half * NN;
    int* offsl = offs   + (size_t)half * NN;

    for (int n = tid; n < NPB; n += 256) cnt[n] = 0;
    __syncthreads();
    for (int i = tid; i < tot; i += 256)
        atomicAdd(&cnt[pb[i] >> 17], 1);
    __syncthreads();

    int a0 = cnt[2 * tid], a1 = cnt[2 * tid + 1];
    int s = a0 + a1;
    ssc[tid] = s;
    __syncthreads();
    for (int off = 1; off < 256; off <<= 1) {
        int t = 0;
        if (tid >= off) t = ssc[tid - off];
        __syncthreads();
        if (tid >= off) ssc[tid] += t;
        __syncthreads();
    }
    int pre = ssc[tid] - s;
    loff[2 * tid]     = pre;
    loff[2 * tid + 1] = pre + a0;
    __syncthreads();

    for (int n = tid; n < nb; n += 256) {
        cnts[n0 + n]  = cnt[n];
        offsl[n0 + n] = gbase + loff[n];
    }
    for (int n = tid; n < NPB; n += 256) cnt[n] = 0;   // reuse as cursor
    __syncthreads();

    for (int i = tid; i < tot; i += 256) {
        uint_t p = pb[i];
        int ln  = p >> 17;
        int pos = loff[ln] + atomicAdd(&cnt[ln], 1);
        image[pos] = (int)(p & 0x1FFFFu);
    }
    __syncthreads();
    for (int i = tid; i < tot; i += 256) pb[i] = (uint_t)image[i];
}

// ---------------------------------------------------------------------------
// Frozen aggregate inner pipeline (r6-verified, bit-exact reuse).
// ---------------------------------------------------------------------------
#define AGG_ISSUE(V, J)                                                   \
    do {                                                                  \
        int s_[8];                                                        \
        _Pragma("unroll")                                                 \
        for (int u = 0; u < 8; ++u) {                                     \
            int jj = (J) + u;                                             \
            int jc = jj < cnt ? jj : cnt - 1;                             \
            int sv = (int)csr[start + jc];                                \
            s_[u] = jj < cnt ? sv : NN;                                   \
        }                                                                 \
        _Pragma("unroll")                                                 \
        for (int u = 0; u < 8; ++u)                                       \
            V[u] = *(const uint4*)(hl + (size_t)s_[u] * DD);              \
    } while (0)

#define AGG_ACCUM(V)                                                      \
    do {                                                                  \
        _Pragma("unroll")                                                 \
        for (int u = 0; u < 8; ++u) {                                     \
            a0 += bflo(V[u].x); a1 += bfhi(V[u].x);                       \
            a2 += bflo(V[u].y); a3 += bfhi(V[u].y);                       \
            a4 += bflo(V[u].z); a5 += bfhi(V[u].z);                       \
            a6 += bflo(V[u].w); a7 += bfhi(V[u].w);                       \
        }                                                                 \
    } while (0)

// ---------------------------------------------------------------------------
// FUSED layer (1/2): per block of 128 nodes, Phase A aggregates neighbor
// means into LDS (frozen pipeline -> bit-identical means, bf16), Phase B
// does the dual GEMM: neighbor chunks first (A-frags ds_read from Mean,
// W staged), then self chunks (A staged from h_in). Kills the 51 MB mean
// HBM round-trip and lets gather-phase blocks overlap MFMA-phase blocks.
// Mean stride 136 bf16 (272 B = 17x16 B): aligned b128 reads, bank pattern
// 4(r+q) mod 32 -> 8 distinct 16B slots = conflict-free floor.
// LDS: Mean 34816 + Wt 8192 + At 8192 = 51200 -> 3 blocks/CU (12 waves).
// ---------------------------------------------------------------------------
template <bool RELU>
__global__ __launch_bounds__(256, 3) void fused_layer(
    const ushort_t* __restrict__ hin, const uint_t* __restrict__ csr,
    const int* __restrict__ offs, const int* __restrict__ counts,
    const ushort_t* __restrict__ W, const float* __restrict__ bias,
    ushort_t* __restrict__ outp)
{
    __shared__ char smem[51200];
    ushort_t* Mean = (ushort_t*)smem;            // [128][136] = 34816 B
    ushort_t* Wt   = (ushort_t*)(smem + 34816);  // 8192 B
    ushort_t* At   = (ushort_t*)(smem + 43008);  // 8192 B (self chunks)
    ushort_t* Ot   = (ushort_t*)smem;            // epilogue: 32768 B

    const int tid  = threadIdx.x;
    const int row0 = blockIdx.x * 128;

    // ======== Phase A: aggregate 128 node-means into Mean (LDS) ========
    {
        const int grp    = tid >> 4;
        const int lane16 = tid & 15;
        const ushort_t* __restrict__ hl = hin + lane16 * 8;
#pragma unroll 1
        for (int g = 0; g < 8; ++g) {
            int nloc = g * 16 + grp;
            int node = row0 + nloc;
            if (node >= NN) node = NN - 1;   // OOB rows discarded in epilogue
            int start = offs[node];
            int cnt   = counts[node];

            float a0 = 0.f, a1 = 0.f, a2 = 0.f, a3 = 0.f;
            float a4 = 0.f, a5 = 0.f, a6 = 0.f, a7 = 0.f;
            int nbt = (cnt + 7) >> 3;
            if (nbt > 0) {
                uint4 va[8], vb[8];
                AGG_ISSUE(va, 0);
                int j = 8, b = 1;
                for (; b + 1 < nbt; b += 2) {
                    AGG_ISSUE(vb, j); j += 8;
                    AGG_ACCUM(va);
                    AGG_ISSUE(va, j); j += 8;
                    AGG_ACCUM(vb);
                }
                if (b < nbt) {
                    AGG_ISSUE(vb, j);
                    AGG_ACCUM(va);
                    AGG_ACCUM(vb);
                } else {
                    AGG_ACCUM(va);
                }
            }
            float rinv = 1.0f / (float)(cnt > 1 ? cnt : 1);
            uint4 o;
            o.x = pack2bf(a0 * rinv, a1 * rinv);
            o.y = pack2bf(a2 * rinv, a3 * rinv);
            o.z = pack2bf(a4 * rinv, a5 * rinv);
            o.w = pack2bf(a6 * rinv, a7 * rinv);
            *(uint4*)(&Mean[nloc * 136 + lane16 * 8]) = o;
        }
    }

    // ======== Phase B: dual GEMM over K=256 (neigh 128..255, self 0..127)
    const int lane = tid & 63;
    const int wav  = tid >> 6;
    const int m0   = (wav & 1) * 64;
    const int n0   = (wav >> 1) * 64;
    const int cl   = lane & 15;
    const int q    = lane >> 4;

    f32x4 acc[4][4];
#pragma unroll
    for (int i = 0; i < 4; ++i)
#pragma unroll
        for (int j = 0; j < 4; ++j) acc[i][j] = (f32x4){0.f, 0.f, 0.f, 0.f};

    __syncthreads();   // Mean visible to all waves

    // -- neighbor chunks (ch 4..7): A from Mean, W[kW=128..255] staged
#pragma unroll 1
    for (int ch = 4; ch < 8; ++ch) {
        const int kA = (ch & 3) * 32;
        const int kW = ch * 32;
        if (ch > 4) __syncthreads();    // Wt safe to overwrite
#pragma unroll
        for (int j = 0; j < 2; ++j) {
            int cb = (j * 4 + wav) * 64;
            int c  = cb + lane;
            int r  = c >> 2, k2 = c & 3;
            gload16(W + (size_t)r * 256 + kW + k2 * 8, Wt + cb * 8);
        }
        __syncthreads();                // drains vmcnt (gload_lds)

        bf16x8 af[4], bfr[4];
#pragma unroll
        for (int i = 0; i < 4; ++i)
            af[i] = *(const bf16x8*)(&Mean[(m0 + i * 16 + cl) * 136 + kA + q * 8]);
#pragma unroll
        for (int j = 0; j < 4; ++j)
            bfr[j] = *(const bf16x8*)(&Wt[(n0 + j * 16 + cl) * 32 + q * 8]);
#pragma unroll
        for (int i = 0; i < 4; ++i)
#pragma unroll
            for (int j = 0; j < 4; ++j)
                acc[i][j] = __builtin_amdgcn_mfma_f32_16x16x32_bf16(
                    af[i], bfr[j], acc[i][j], 0, 0, 0);
    }

    // -- self chunks (ch 0..3): A staged from hin, W[kW=0..127] staged
#pragma unroll 1
    for (int ch = 0; ch < 4; ++ch) {
        const int kA = ch * 32;
        __syncthreads();                // prev reads of At/Wt done
#pragma unroll
        for (int j = 0; j < 2; ++j) {
            int cb = (j * 4 + wav) * 64;
            int c  = cb + lane;
            int r  = c >> 2, k2 = c & 3;
            int grow = row0 + r;
            if (grow >= NN) grow = NN - 1;
            gload16(hin + (size_t)grow * DD + kA + k2 * 8, At + cb * 8);
            gload16(W + (size_t)r * 256 + kA + k2 * 8, Wt + cb * 8);
        }
        __syncthreads();

        bf16x8 af[4], bfr[4];
#pragma unroll
        for (int i = 0; i < 4; ++i)
            af[i] = *(const bf16x8*)(&At[(m0 + i * 16 + cl) * 32 + q * 8]);
#pragma unroll
        for (int j = 0; j < 4; ++j)
            bfr[j] = *(const bf16x8*)(&Wt[(n0 + j * 16 + cl) * 32 + q * 8]);
#pragma unroll
        for (int i = 0; i < 4; ++i)
#pragma unroll
            for (int j = 0; j < 4; ++j)
                acc[i][j] = __builtin_amdgcn_mfma_f32_16x16x32_bf16(
                    af[i], bfr[j], acc[i][j], 0, 0, 0);
    }

    // ======== Epilogue (Mean/At/Wt dead; Ot overlays smem) ========
    __syncthreads();
#pragma unroll
    for (int j = 0; j < 4; ++j) {
        int c = n0 + j * 16 + cl;
        float bv = bias[c];
#pragma unroll
        for (int i = 0; i < 4; ++i) {
#pragma unroll
            for (int reg = 0; reg < 4; ++reg) {
                int r = m0 + i * 16 + 4 * q + reg;
                float v = acc[i][j][reg] + bv;
                if constexpr (RELU) v = fmaxf(v, 0.f);
                Ot[r * 128 + c] = f2bf(v);
            }
        }
    }
    __syncthreads();
    int rows = NN - row0; if (rows > 128) rows = 128;
    for (int t = tid; t < rows * 16; t += 256) {
        int r = t >> 4, c8 = (t & 15) * 8;
        *(uint4*)(outp + (size_t)(row0 + r) * DD + c8) =
            *(const uint4*)(&Ot[r * 128 + c8]);
    }
}

// ---------------------------------------------------------------------------
// Fused edge scoring on bf16 h3 (unchanged).
// ---------------------------------------------------------------------------
__device__ __forceinline__ float dot8(uint4 a, uint4 b) {
    return bflo(a.x) * bflo(b.x) + bfhi(a.x) * bfhi(b.x)
         + bflo(a.y) * bflo(b.y) + bfhi(a.y) * bfhi(b.y)
         + bflo(a.z) * bflo(b.z) + bfhi(a.z) * bfhi(b.z)
         + bflo(a.w) * bflo(b.w) + bfhi(a.w) * bfhi(b.w);
}

__global__ __launch_bounds__(256) void score_both(
    const ushort_t* __restrict__ h,
    const int* __restrict__ ps, const int* __restrict__ pd,
    const int* __restrict__ ns, const int* __restrict__ nd,
    float* __restrict__ out, int EP, int TE)
{
    int gid = blockIdx.x * 256 + threadIdx.x;
    int grp = gid >> 4;
    int e0 = grp * 2;
    if (e0 >= TE) return;
    int lane = gid & 15;
    int e1 = e0 + 1;
    bool has1 = (e1 < TE);
    int ee = has1 ? e1 : e0;

    int s0, d0, s1, d1;
    if (e0 < EP) { s0 = ps[e0]; d0 = pd[e0]; }
    else         { s0 = ns[e0 - EP]; d0 = nd[e0 - EP]; }
    if (ee < EP) { s1 = ps[ee]; d1 = pd[ee]; }
    else         { s1 = ns[ee - EP]; d1 = nd[ee - EP]; }

    const ushort_t* __restrict__ hl = h + lane * 8;
    uint4 va0 = *(const uint4*)(hl + (size_t)s0 * DD);
    uint4 vb0 = *(const uint4*)(hl + (size_t)d0 * DD);
    uint4 va1 = *(const uint4*)(hl + (size_t)s1 * DD);
    uint4 vb1 = *(const uint4*)(hl + (size_t)d1 * DD);

    float r0 = dot8(va0, vb0);
    float r1 = dot8(va1, vb1);
#pragma unroll
    for (int off = 8; off; off >>= 1) {
        r0 += __shfl_down(r0, off, 16);
        r1 += __shfl_down(r1, off, 16);
    }
    if (lane == 0) {
        out[e0] = r0;
        if (has1) out[e1] = r1;
    }
}

// ---------------------------------------------------------------------------

extern "C" void kernel_launch(void* const* d_in, const int* in_sizes, int n_in,
                              void* d_out, int out_size, void* d_ws, size_t ws_size,
                              hipStream_t stream)
{
    const float* feat    = (const float*)d_in[0];
    const int*   e0s     = (const int*)d_in[1];
    const int*   e0d     = (const int*)d_in[2];
    const int*   e1s     = (const int*)d_in[3];
    const int*   e1d     = (const int*)d_in[4];
    const int*   ps      = (const int*)d_in[5];
    const int*   pd      = (const int*)d_in[6];
    const int*   ns      = (const int*)d_in[7];
    const int*   nd      = (const int*)d_in[8];
    const float* w_proj  = (const float*)d_in[9];
    const float* b_proj  = (const float*)d_in[10];
    const float* w_self1 = (const float*)d_in[11];
    const float* w_neigh1= (const float*)d_in[12];
    const float* b1      = (const float*)d_in[13];
    const float* w_self2 = (const float*)d_in[14];
    const float* w_neigh2= (const float*)d_in[15];
    const float* b2      = (const float*)d_in[16];

    float* out = (float*)d_out;

    const size_t NF  = (size_t)NN * DD;
    const size_t NFP = NF + DD;          // +1 pad row (index NN, zeroed)
    char* base = (char*)d_ws;

    // bf16 buffers, NFP*2 bytes each.
    ushort_t* h3   = (ushort_t*)base;
    ushort_t* h1   = h3 + NFP;
    ushort_t* mean = h1 + NFP;           // (unused by fused path; kept)
    ushort_t* h2   = mean + NFP;

    uint_t* pairs  = (uint_t*)(h2 + NFP);                // 2*NB*CAPB*4 = 19.3 MB
    int*    bcnt   = (int*)(pairs + (size_t)2 * NB * CAPB);   // [2*NB]
    int*    counts = bcnt + 2 * NB;                      // [2*NN]
    int*    offs   = counts + 2 * NN;                    // [2*NN]
    ushort_t* wts  = (ushort_t*)(offs + 2 * NN);
    ushort_t* wtp = wts;                 // [128][128]
    ushort_t* wt1 = wts + 128 * 128;     // [128][256]
    ushort_t* wt2 = wt1 + 128 * 256;     // [128][256]

    const int E0 = in_sizes[1];
    const int E1 = in_sizes[3];
    const int EP = in_sizes[5];
    const int EN = in_sizes[7];

    // ---- Prep: weight transposes + bcnt zero + pad-row zero
    prep<<<PREP_W_BLOCKS + PREP_Z_BLOCKS, 256, 0, stream>>>(
        w_proj, w_self1, w_neigh1, w_self2, w_neigh2, wtp, wt1, wt2, bcnt,
        h1 + NF, h2 + NF);

    // ---- Build both CSRs (r6 config)
    partA2<<<2 * PA_BLOCKS, 256, 0, stream>>>(
        e0s, e0d, E0, e1s, e1d, E1, bcnt, pairs);
    partB<<<2 * NB, 256, 0, stream>>>(pairs, bcnt, counts, offs);

    // ---- Layer 0: h1 = relu(feat @ w_proj + b_proj)
    gemm0<<<GBLK, 256, 0, stream>>>(feat, wtp, b_proj, h1);

    // ---- Layer 1: fused aggregate(edge0) + dual GEMM
    fused_layer<true><<<GBLK, 256, 0, stream>>>(
        h1, pairs, offs, counts, wt1, b1, h2);

    // ---- Layer 2: fused aggregate(edge1) + dual GEMM
    fused_layer<false><<<GBLK, 256, 0, stream>>>(
        h2, pairs, offs + NN, counts + NN, wt2, b2, h3);

    // ---- Fused scoring on bf16 h3
    const int TE = EP + EN;
    const int NG = (TE + 1) / 2;
    score_both<<<(NG * 16 + 255) / 256, 256, 0, stream>>>(
        h3, ps, pd, ns, nd, out, EP, TE);
}

// Round 12
// 387.743 us; speedup vs baseline: 1.0896x; 1.0896x over previous
//
#include <hip/hip_runtime.h>
#include <hip/hip_bf16.h>

#define NN 100000
#define DD 128

// Bucketed CSR build: 512 nodes per bucket
#define NPB 512
#define NB 196                     // ceil(100000/512)
#define CAPB 12288                 // pairs/bucket (mean 8192, huge slack)
#define PA_BLOCKS 196              // 196-block edge partition is the measured
                                   // optimum for write locality (784 -> 3.6x
                                   // write amp r7; counting sort -> 16x r8).
                                   // TLP comes from 512-thread blocks instead.
#define GBLK 782                   // ceil(NN/128)

typedef unsigned short ushort_t;
typedef unsigned int uint_t;
typedef __attribute__((ext_vector_type(8))) short bf16x8;
typedef __attribute__((ext_vector_type(4))) float f32x4;

__device__ __forceinline__ ushort_t f2bf(float f) {
    uint_t u = __builtin_bit_cast(uint_t, f);
    u += 0x7FFFu + ((u >> 16) & 1u);          // RNE
    return (ushort_t)(u >> 16);
}
__device__ __forceinline__ uint_t pack2bf(float a, float b) {
    return (uint_t)f2bf(a) | ((uint_t)f2bf(b) << 16);
}
__device__ __forceinline__ float bflo(uint_t v) {
    return __builtin_bit_cast(float, v << 16);
}
__device__ __forceinline__ float bfhi(uint_t v) {
    return __builtin_bit_cast(float, v & 0xFFFF0000u);
}

// async global->LDS, 16 B per lane (dest = wave-uniform base + lane*16).
__device__ __forceinline__ void gload16(const ushort_t* g, ushort_t* l) {
    __builtin_amdgcn_global_load_lds(
        (const __attribute__((address_space(1))) void*)g,
        (__attribute__((address_space(3))) void*)l,
        16, 0, 0);
}

// ---------------------------------------------------------------------------
// prep: weight transposes (blocks 0..319) + bcnt zeroing (320..321) +
// zero pad-row NN of h1/h2 (block 322).
// ---------------------------------------------------------------------------
#define PREP_W_BLOCKS 320
#define PREP_Z_BLOCKS 3
__global__ __launch_bounds__(256) void prep(
    const float* __restrict__ w_proj,
    const float* __restrict__ w_self1, const float* __restrict__ w_neigh1,
    const float* __restrict__ w_self2, const float* __restrict__ w_neigh2,
    ushort_t* __restrict__ wtp, ushort_t* __restrict__ wt1,
    ushort_t* __restrict__ wt2, int* __restrict__ bcnt,
    ushort_t* __restrict__ h1pad, ushort_t* __restrict__ h2pad)
{
    const int bid = blockIdx.x;
    const int tid = threadIdx.x;
    if (bid < PREP_W_BLOCKS) {
        int which = bid >> 6;                 // 0..4
        int t = (bid & 63) * 256 + tid;       // 0..16383
        int n = t >> 7, k = t & 127;
        float v;
        ushort_t* d;
        switch (which) {
            case 0: v = w_proj  [(size_t)k * 128 + n]; d = wtp + (size_t)n * 128 + k;       break;
            case 1: v = w_self1 [(size_t)k * 128 + n]; d = wt1 + (size_t)n * 256 + k;       break;
            case 2: v = w_neigh1[(size_t)k * 128 + n]; d = wt1 + (size_t)n * 256 + 128 + k; break;
            case 3: v = w_self2 [(size_t)k * 128 + n]; d = wt2 + (size_t)n * 256 + k;       break;
            default:v = w_neigh2[(size_t)k * 128 + n]; d = wt2 + (size_t)n * 256 + 128 + k; break;
        }
        *d = f2bf(v);
    } else if (bid < PREP_W_BLOCKS + 2) {
        int i = (bid - PREP_W_BLOCKS) * 256 + tid;
        if (i < 2 * NB) bcnt[i] = 0;
    } else {
        uint_t* p1 = (uint_t*)h1pad;
        uint_t* p2 = (uint_t*)h2pad;
        if (tid < 64) p1[tid] = 0;
        else if (tid < 128) p2[tid - 64] = 0;
    }
}

// ---------------------------------------------------------------------------
// gemm0 (layer 0, CVT): h1 = relu(feat @ Wp + b). fp32 A reg-converted,
// W via gload_lds, single-buffer (r6-verified path).
// ---------------------------------------------------------------------------
__global__ __launch_bounds__(256, 4) void gemm0(
    const float* __restrict__ feat, const ushort_t* __restrict__ W,
    const float* __restrict__ bias, ushort_t* __restrict__ outp)
{
    __shared__ char smem[32768];
    ushort_t* At = (ushort_t*)smem;             // 128*32*2 = 8192 B
    ushort_t* Wt = (ushort_t*)(smem + 8192);    // 8192 B
    ushort_t* Ot = (ushort_t*)smem;             // epilogue: full 32 KB

    const int tid  = threadIdx.x;
    const int lane = tid & 63;
    const int wav  = tid >> 6;
    const int row0 = blockIdx.x * 128;
    const int m0   = (wav & 1) * 64;
    const int n0   = (wav >> 1) * 64;

    f32x4 acc[4][4];
#pragma unroll
    for (int i = 0; i < 4; ++i)
#pragma unroll
        for (int j = 0; j < 4; ++j) acc[i][j] = (f32x4){0.f, 0.f, 0.f, 0.f};

    const int cl = lane & 15;
    const int q  = lane >> 4;

#pragma unroll 1
    for (int ch = 0; ch < 4; ++ch) {
        const int kA = ch * 32;

        if (ch) __syncthreads();
#pragma unroll
        for (int j = 0; j < 2; ++j) {
            int cb = (j * 4 + wav) * 64;
            int c  = cb + lane;
            int r  = c >> 2, k2 = c & 3;
            gload16(W + (size_t)r * 128 + kA + k2 * 8, Wt + cb * 8);
        }
        uint4 av[2];
#pragma unroll
        for (int j = 0; j < 2; ++j) {
            int g = tid + 256 * j;
            int r = g >> 2;
            int c = (g & 3) * 8;
            int grow = row0 + r;
            if (grow >= NN) grow = NN - 1;
            float4 f0 = *(const float4*)(feat + (size_t)grow * DD + kA + c);
            float4 f1 = *(const float4*)(feat + (size_t)grow * DD + kA + c + 4);
            av[j].x = pack2bf(f0.x, f0.y);
            av[j].y = pack2bf(f0.z, f0.w);
            av[j].z = pack2bf(f1.x, f1.y);
            av[j].w = pack2bf(f1.z, f1.w);
        }
#pragma unroll
        for (int j = 0; j < 2; ++j) {
            int g = tid + 256 * j;
            int r = g >> 2;
            int c = (g & 3) * 8;
            *(uint4*)(&At[r * 32 + c]) = av[j];
        }
        __syncthreads();

        bf16x8 af[4], bfr[4];
#pragma unroll
        for (int i = 0; i < 4; ++i)
            af[i] = *(const bf16x8*)(&At[(m0 + i * 16 + cl) * 32 + q * 8]);
#pragma unroll
        for (int j = 0; j < 4; ++j)
            bfr[j] = *(const bf16x8*)(&Wt[(n0 + j * 16 + cl) * 32 + q * 8]);
#pragma unroll
        for (int i = 0; i < 4; ++i)
#pragma unroll
            for (int j = 0; j < 4; ++j)
                acc[i][j] = __builtin_amdgcn_mfma_f32_16x16x32_bf16(
                    af[i], bfr[j], acc[i][j], 0, 0, 0);
    }

    // Epilogue. C/D layout: col=lane&15, row=(lane>>4)*4+reg  [m89/m91]
    __syncthreads();
#pragma unroll
    for (int j = 0; j < 4; ++j) {
        int c = n0 + j * 16 + cl;
        float bv = bias[c];
#pragma unroll
        for (int i = 0; i < 4; ++i) {
#pragma unroll
            for (int reg = 0; reg < 4; ++reg) {
                int r = m0 + i * 16 + 4 * q + reg;
                float v = acc[i][j][reg] + bv;
                v = fmaxf(v, 0.f);
                Ot[r * 128 + c] = f2bf(v);
            }
        }
    }
    __syncthreads();
    int rows = NN - row0; if (rows > 128) rows = 128;
    for (int t = tid; t < rows * 16; t += 256) {
        int r = t >> 4, c8 = (t & 15) * 8;
        *(uint4*)(outp + (size_t)(row0 + r) * DD + c8) =
            *(const uint4*)(&Ot[r * 128 + c8]);
    }
}

// ---------------------------------------------------------------------------
// partA2: bin BOTH edge lists into 512-node buckets. 512 threads/block
// (was 256): doubles waves/CU WITHOUT changing the per-block edge range —
// bucket write runs (and thus WRITE_SIZE) stay identical to the r6 optimum.
// ---------------------------------------------------------------------------
__global__ __launch_bounds__(512) void partA2(
    const int* __restrict__ e0s, const int* __restrict__ e0d, int E0,
    const int* __restrict__ e1s, const int* __restrict__ e1d, int E1,
    int* __restrict__ bcnt, uint_t* __restrict__ pairs)
{
    __shared__ int hist[NB];
    __shared__ int base[NB];
    const int tid  = threadIdx.x;
    const int half = blockIdx.x >= PA_BLOCKS;
    const int* __restrict__ src = half ? e1s : e0s;
    const int* __restrict__ dst = half ? e1d : e0d;
    const int E = half ? E1 : E0;
    int* bc = bcnt + half * NB;
    uint_t* pp = pairs + (size_t)half * NB * CAPB;
    const int blk = blockIdx.x - half * PA_BLOCKS;
    const int chunk = (E + PA_BLOCKS - 1) / PA_BLOCKS;
    const int ea = blk * chunk;
    int eb = ea + chunk; if (eb > E) eb = E;

    for (int b = tid; b < NB; b += 512) hist[b] = 0;
    __syncthreads();
    for (int e = ea + tid; e < eb; e += 512)
        atomicAdd(&hist[dst[e] >> 9], 1);
    __syncthreads();
    for (int b = tid; b < NB; b += 512) {
        base[b] = atomicAdd(&bc[b], hist[b]);
        hist[b] = 0;
    }
    __syncthreads();
    for (int e = ea + tid; e < eb; e += 512) {
        int d = dst[e];
        int b = d >> 9;
        int off = atomicAdd(&hist[b], 1);
        int p = base[b] + off;
        if (p < CAPB)
            pp[(size_t)b * CAPB + p] =
                ((uint_t)(d & (NPB - 1)) << 17) | (uint_t)src[e];
    }
}

// ---------------------------------------------------------------------------
// partB: one block per bucket (392 blocks), now 512 threads/block (2x TLP;
// LDS 55 KB -> still 2 blocks/CU but 16 waves). Scan redone 1-elem/thread.
// ---------------------------------------------------------------------------
__global__ __launch_bounds__(512) void partB(
    uint_t* __restrict__ pairs, const int* __restrict__ bcnt,
    int* __restrict__ counts, int* __restrict__ offs)
{
    __shared__ int cnt[NPB];
    __shared__ int loff[NPB];
    __shared__ int ssc[NPB];
    __shared__ int image[CAPB];

    const int tid  = threadIdx.x;
    const int half = blockIdx.x >= NB;
    const int b    = blockIdx.x - half * NB;
    const int n0   = b << 9;
    int nb = NN - n0; if (nb > NPB) nb = NPB;
    int tot = bcnt[half * NB + b]; if (tot > CAPB) tot = CAPB;
    uint_t* pb = pairs + (size_t)(half * NB + b) * CAPB;
    const int gbase = (half * NB + b) * CAPB;
    int* cnts  = counts + (size_t)half * NN;
    int* offsl = offs   + (size_t)half * NN;

    cnt[tid] = 0;                       // NPB == 512 == blockDim
    __syncthreads();
    for (int i = tid; i < tot; i += 512)
        atomicAdd(&cnt[pb[i] >> 17], 1);
    __syncthreads();

    // exclusive scan over 512 bins, 1 element/thread (Hillis-Steele)
    int s = cnt[tid];
    ssc[tid] = s;
    __syncthreads();
    for (int off = 1; off < NPB; off <<= 1) {
        int t = 0;
        if (tid >= off) t = ssc[tid - off];
        __syncthreads();
        if (tid >= off) ssc[tid] += t;
        __syncthreads();
    }
    loff[tid] = ssc[tid] - s;
    __syncthreads();

    if (tid < nb) {
        cnts[n0 + tid]  = cnt[tid];
        offsl[n0 + tid] = gbase + loff[tid];
    }
    cnt[tid] = 0;                       // reuse as cursor
    __syncthreads();

    for (int i = tid; i < tot; i += 512) {
        uint_t p = pb[i];
        int ln  = p >> 17;
        int pos = loff[ln] + atomicAdd(&cnt[ln], 1);
        image[pos] = (int)(p & 0x1FFFFu);
    }
    __syncthreads();
    for (int i = tid; i < tot; i += 512) pb[i] = (uint_t)image[i];
}

// ---------------------------------------------------------------------------
// bf16 MFMA GEMM (layers 1/2): out = act( [A | Bm] @ W + bias ).
// 2-phase double-buffered gload_lds staging (r6-verified, ~22 µs).
// ---------------------------------------------------------------------------
template <bool RELU>
__global__ __launch_bounds__(256, 4) void gemm_bf16(
    const ushort_t* __restrict__ Av, const ushort_t* __restrict__ Bm,
    const ushort_t* __restrict__ W, const float* __restrict__ bias,
    ushort_t* __restrict__ outp)
{
    __shared__ char smem[32768];
    ushort_t* Ot = (ushort_t*)smem;             // epilogue: full 32 KB

    const int tid  = threadIdx.x;
    const int lane = tid & 63;
    const int wav  = tid >> 6;
    const int row0 = blockIdx.x * 128;
    const int m0   = (wav & 1) * 64;
    const int n0   = (wav >> 1) * 64;
    const int KTOT = 256;
    const int NCH  = 8;

    f32x4 acc[4][4];
#pragma unroll
    for (int i = 0; i < 4; ++i)
#pragma unroll
        for (int j = 0; j < 4; ++j) acc[i][j] = (f32x4){0.f, 0.f, 0.f, 0.f};

    const int cl = lane & 15;
    const int q  = lane >> 4;

    auto STAGE = [&](int ch, int buf) {
        const bool second = (ch >= 4);
        const int kA = (ch & 3) * 32;
        const int kW = ch * 32;
        ushort_t* At = (ushort_t*)(smem + buf * 16384);
        ushort_t* Wt = At + 4096;            // +8192 bytes
        const ushort_t* sp = second ? Bm : Av;
#pragma unroll
        for (int j = 0; j < 2; ++j) {
            int cb = (j * 4 + wav) * 64;
            int c  = cb + lane;
            int r  = c >> 2, k2 = c & 3;
            int grow = row0 + r;
            if (grow >= NN) grow = NN - 1;
            gload16(sp + (size_t)grow * DD + kA + k2 * 8, At + cb * 8);
            gload16(W + (size_t)r * KTOT + kW + k2 * 8, Wt + cb * 8);
        }
    };
    auto COMPUTE = [&](int buf) {
        ushort_t* At = (ushort_t*)(smem + buf * 16384);
        ushort_t* Wt = At + 4096;
        bf16x8 af[4], bfr[4];
#pragma unroll
        for (int i = 0; i < 4; ++i)
            af[i] = *(const bf16x8*)(&At[(m0 + i * 16 + cl) * 32 + q * 8]);
#pragma unroll
        for (int j = 0; j < 4; ++j)
            bfr[j] = *(const bf16x8*)(&Wt[(n0 + j * 16 + cl) * 32 + q * 8]);
#pragma unroll
        for (int i = 0; i < 4; ++i)
#pragma unroll
            for (int j = 0; j < 4; ++j)
                acc[i][j] = __builtin_amdgcn_mfma_f32_16x16x32_bf16(
                    af[i], bfr[j], acc[i][j], 0, 0, 0);
    };

    STAGE(0, 0);
    asm volatile("s_waitcnt vmcnt(0)" ::: "memory");
    __builtin_amdgcn_s_barrier();
    int cur = 0;
#pragma unroll 1
    for (int ch = 0; ch < NCH - 1; ++ch) {
        STAGE(ch + 1, cur ^ 1);   // issue next-chunk loads (other buffer)
        COMPUTE(cur);             // ds_read+MFMA current
        asm volatile("s_waitcnt vmcnt(0)" ::: "memory");
        __builtin_amdgcn_s_barrier();
        cur ^= 1;
    }
    COMPUTE(cur);                 // last chunk, no prefetch

    // Epilogue. C/D layout: col=lane&15, row=(lane>>4)*4+reg  [m89/m91]
    __syncthreads();
#pragma unroll
    for (int j = 0; j < 4; ++j) {
        int c = n0 + j * 16 + cl;
        float bv = bias[c];
#pragma unroll
        for (int i = 0; i < 4; ++i) {
#pragma unroll
            for (int reg = 0; reg < 4; ++reg) {
                int r = m0 + i * 16 + 4 * q + reg;
                float v = acc[i][j][reg] + bv;
                if constexpr (RELU) v = fmaxf(v, 0.f);
                Ot[r * 128 + c] = f2bf(v);
            }
        }
    }
    __syncthreads();
    int rows = NN - row0; if (rows > 128) rows = 128;
    for (int t = tid; t < rows * 16; t += 256) {
        int r = t >> 4, c8 = (t & 15) * 8;
        *(uint4*)(outp + (size_t)(row0 + r) * DD + c8) =
            *(const uint4*)(&Ot[r * 128 + c8]);
    }
}

// ---------------------------------------------------------------------------
// CSR mean-aggregate over bf16 h (best measured: 57.4 µs @ r6, FROZEN —
// at the random-gather service ceiling; r2-r4: MLP null, guards small win,
// TLP cut regression, r10 in-LDS fusion regression).
// ---------------------------------------------------------------------------
#define AGG_ISSUE(V, J)                                                   \
    do {                                                                  \
        int s_[8];                                                        \
        _Pragma("unroll")                                                 \
        for (int u = 0; u < 8; ++u) {                                     \
            int jj = (J) + u;                                             \
            int jc = jj < cnt ? jj : cnt - 1;                             \
            int sv = (int)csr[start + jc];                                \
            s_[u] = jj < cnt ? sv : NN;                                   \
        }                                                                 \
        _Pragma("unroll")                                                 \
        for (int u = 0; u < 8; ++u)                                       \
            V[u] = *(const uint4*)(hl + (size_t)s_[u] * DD);              \
    } while (0)

#define AGG_ACCUM(V)                                                      \
    do {                                                                  \
        _Pragma("unroll")                                                 \
        for (int u = 0; u < 8; ++u) {                                     \
            a0 += bflo(V[u].x); a1 += bfhi(V[u].x);                       \
            a2 += bflo(V[u].y); a3 += bfhi(V[u].y);                       \
            a4 += bflo(V[u].z); a5 += bfhi(V[u].z);                       \
            a6 += bflo(V[u].w); a7 += bfhi(V[u].w);                       \
        }                                                                 \
    } while (0)

__global__ __launch_bounds__(256) void aggregate_bf16(
    const ushort_t* __restrict__ h, const uint_t* __restrict__ csr,
    const int* __restrict__ offs, const int* __restrict__ counts,
    ushort_t* __restrict__ mean, int nn)
{
    int gid  = blockIdx.x * 256 + threadIdx.x;
    int node = gid >> 4;
    if (node >= nn) return;
    int lane  = gid & 15;
    int start = offs[node];
    int cnt   = counts[node];
    const ushort_t* __restrict__ hl = h + lane * 8;

    float a0 = 0.f, a1 = 0.f, a2 = 0.f, a3 = 0.f;
    float a4 = 0.f, a5 = 0.f, a6 = 0.f, a7 = 0.f;

    int nbt = (cnt + 7) >> 3;        // number of (padded) 8-batches
    if (nbt > 0) {
        uint4 va[8], vb[8];
        AGG_ISSUE(va, 0);
        int j = 8, b = 1;
        for (; b + 1 < nbt; b += 2) {
            AGG_ISSUE(vb, j); j += 8;      // batch B in flight...
            AGG_ACCUM(va);                 // ...while A is consumed
            AGG_ISSUE(va, j); j += 8;
            AGG_ACCUM(vb);
        }
        if (b < nbt) {                     // one trailing issued batch
            AGG_ISSUE(vb, j);
            AGG_ACCUM(va);
            AGG_ACCUM(vb);
        } else {
            AGG_ACCUM(va);
        }
    }

    float rinv = 1.0f / (float)(cnt > 1 ? cnt : 1);
    uint4 o;
    o.x = pack2bf(a0 * rinv, a1 * rinv);
    o.y = pack2bf(a2 * rinv, a3 * rinv);
    o.z = pack2bf(a4 * rinv, a5 * rinv);
    o.w = pack2bf(a6 * rinv, a7 * rinv);
    *(uint4*)(mean + (size_t)node * DD + lane * 8) = o;
}

// ---------------------------------------------------------------------------
// Fused edge scoring on bf16 h3 (at the same gather service ceiling, FROZEN).
// ---------------------------------------------------------------------------
__device__ __forceinline__ float dot8(uint4 a, uint4 b) {
    return bflo(a.x) * bflo(b.x) + bfhi(a.x) * bfhi(b.x)
         + bflo(a.y) * bflo(b.y) + bfhi(a.y) * bfhi(b.y)
         + bflo(a.z) * bflo(b.z) + bfhi(a.z) * bfhi(b.z)
         + bflo(a.w) * bflo(b.w) + bfhi(a.w) * bfhi(b.w);
}

__global__ __launch_bounds__(256) void score_both(
    const ushort_t* __restrict__ h,
    const int* __restrict__ ps, const int* __restrict__ pd,
    const int* __restrict__ ns, const int* __restrict__ nd,
    float* __restrict__ out, int EP, int TE)
{
    int gid = blockIdx.x * 256 + threadIdx.x;
    int grp = gid >> 4;
    int e0 = grp * 2;
    if (e0 >= TE) return;
    int lane = gid & 15;
    int e1 = e0 + 1;
    bool has1 = (e1 < TE);
    int ee = has1 ? e1 : e0;

    int s0, d0, s1, d1;
    if (e0 < EP) { s0 = ps[e0]; d0 = pd[e0]; }
    else         { s0 = ns[e0 - EP]; d0 = nd[e0 - EP]; }
    if (ee < EP) { s1 = ps[ee]; d1 = pd[ee]; }
    else         { s1 = ns[ee - EP]; d1 = nd[ee - EP]; }

    const ushort_t* __restrict__ hl = h + lane * 8;
    uint4 va0 = *(const uint4*)(hl + (size_t)s0 * DD);
    uint4 vb0 = *(const uint4*)(hl + (size_t)d0 * DD);
    uint4 va1 = *(const uint4*)(hl + (size_t)s1 * DD);
    uint4 vb1 = *(const uint4*)(hl + (size_t)d1 * DD);

    float r0 = dot8(va0, vb0);
    float r1 = dot8(va1, vb1);
#pragma unroll
    for (int off = 8; off; off >>= 1) {
        r0 += __shfl_down(r0, off, 16);
        r1 += __shfl_down(r1, off, 16);
    }
    if (lane == 0) {
        out[e0] = r0;
        if (has1) out[e1] = r1;
    }
}

// ---------------------------------------------------------------------------

extern "C" void kernel_launch(void* const* d_in, const int* in_sizes, int n_in,
                              void* d_out, int out_size, void* d_ws, size_t ws_size,
                              hipStream_t stream)
{
    const float* feat    = (const float*)d_in[0];
    const int*   e0s     = (const int*)d_in[1];
    const int*   e0d     = (const int*)d_in[2];
    const int*   e1s     = (const int*)d_in[3];
    const int*   e1d     = (const int*)d_in[4];
    const int*   ps      = (const int*)d_in[5];
    const int*   pd      = (const int*)d_in[6];
    const int*   ns      = (const int*)d_in[7];
    const int*   nd      = (const int*)d_in[8];
    const float* w_proj  = (const float*)d_in[9];
    const float* b_proj  = (const float*)d_in[10];
    const float* w_self1 = (const float*)d_in[11];
    const float* w_neigh1= (const float*)d_in[12];
    const float* b1      = (const float*)d_in[13];
    const float* w_self2 = (const float*)d_in[14];
    const float* w_neigh2= (const float*)d_in[15];
    const float* b2      = (const float*)d_in[16];

    float* out = (float*)d_out;

    const size_t NF  = (size_t)NN * DD;
    const size_t NFP = NF + DD;          // +1 pad row (index NN, zeroed)
    char* base = (char*)d_ws;

    // bf16 buffers, NFP*2 bytes each (pad row NN for unguarded aggregate).
    ushort_t* h3   = (ushort_t*)base;
    ushort_t* h1   = h3 + NFP;
    ushort_t* mean = h1 + NFP;
    ushort_t* h2   = mean + NFP;

    uint_t* pairs  = (uint_t*)(h2 + NFP);                // 2*NB*CAPB*4 = 19.3 MB
    int*    bcnt   = (int*)(pairs + (size_t)2 * NB * CAPB);   // [2*NB]
    int*    counts = bcnt + 2 * NB;                      // [2*NN]
    int*    offs   = counts + 2 * NN;                    // [2*NN]
    ushort_t* wts  = (ushort_t*)(offs + 2 * NN);
    ushort_t* wtp = wts;                 // [128][128]
    ushort_t* wt1 = wts + 128 * 128;     // [128][256]
    ushort_t* wt2 = wt1 + 128 * 256;     // [128][256]

    const int E0 = in_sizes[1];
    const int E1 = in_sizes[3];
    const int EP = in_sizes[5];
    const int EN = in_sizes[7];

    const int AGB = (NN * 16 + 255) / 256;

    // ---- Prep: weight transposes + bcnt zero + pad-row zero
    prep<<<PREP_W_BLOCKS + PREP_Z_BLOCKS, 256, 0, stream>>>(
        w_proj, w_self1, w_neigh1, w_self2, w_neigh2, wtp, wt1, wt2, bcnt,
        h1 + NF, h2 + NF);

    // ---- Build both CSRs (196-block partition, 512-thread blocks)
    partA2<<<2 * PA_BLOCKS, 512, 0, stream>>>(
        e0s, e0d, E0, e1s, e1d, E1, bcnt, pairs);
    partB<<<2 * NB, 512, 0, stream>>>(pairs, bcnt, counts, offs);

    // ---- Layer 0: h1 = relu(feat @ w_proj + b_proj)
    gemm0<<<GBLK, 256, 0, stream>>>(feat, wtp, b_proj, h1);

    // ---- Layer 1: mean over edge0, then dual GEMM
    aggregate_bf16<<<AGB, 256, 0, stream>>>(h1, pairs, offs, counts, mean, NN);
    gemm_bf16<true><<<GBLK, 256, 0, stream>>>(h1, mean, wt1, b1, h2);

    // ---- Layer 2: mean over edge1, then dual GEMM
    aggregate_bf16<<<AGB, 256, 0, stream>>>(
        h2, pairs, offs + NN, counts + NN, mean, NN);
    gemm_bf16<false><<<GBLK, 256, 0, stream>>>(h2, mean, wt2, b2, h3);

    // ---- Fused scoring on bf16 h3
    const int TE = EP + EN;
    const int NG = (TE + 1) / 2;
    score_both<<<(NG * 16 + 255) / 256, 256, 0, stream>>>(
        h3, ps, pd, ns, nd, out, EP, TE);
}

// Round 13
// 382.477 us; speedup vs baseline: 1.1046x; 1.0138x over previous
//
#include <hip/hip_runtime.h>
#include <hip/hip_bf16.h>

#define NN 100000
#define DD 128

// Bucketed CSR build: 512 nodes per bucket
#define NPB 512
#define NB 196                     // ceil(100000/512)
#define CAPB 12288                 // pairs/bucket (mean 8192, huge slack)
#define PA_BLOCKS 196              // 196-block edge partition is the measured
                                   // optimum for write locality (784 -> 3.6x
                                   // write amp r7; counting sort -> 16x r8).
                                   // TLP scaling via threads/block: 256->512
                                   // was +11 µs total (r12); now 1024.
#define GBLK 782                   // ceil(NN/128)

typedef unsigned short ushort_t;
typedef unsigned int uint_t;
typedef __attribute__((ext_vector_type(8))) short bf16x8;
typedef __attribute__((ext_vector_type(4))) float f32x4;

__device__ __forceinline__ ushort_t f2bf(float f) {
    uint_t u = __builtin_bit_cast(uint_t, f);
    u += 0x7FFFu + ((u >> 16) & 1u);          // RNE
    return (ushort_t)(u >> 16);
}
__device__ __forceinline__ uint_t pack2bf(float a, float b) {
    return (uint_t)f2bf(a) | ((uint_t)f2bf(b) << 16);
}
__device__ __forceinline__ float bflo(uint_t v) {
    return __builtin_bit_cast(float, v << 16);
}
__device__ __forceinline__ float bfhi(uint_t v) {
    return __builtin_bit_cast(float, v & 0xFFFF0000u);
}

// async global->LDS, 16 B per lane (dest = wave-uniform base + lane*16).
__device__ __forceinline__ void gload16(const ushort_t* g, ushort_t* l) {
    __builtin_amdgcn_global_load_lds(
        (const __attribute__((address_space(1))) void*)g,
        (__attribute__((address_space(3))) void*)l,
        16, 0, 0);
}

// ---------------------------------------------------------------------------
// prep: weight transposes (blocks 0..319) + bcnt zeroing (320..321) +
// zero pad-row NN of h1/h2 (block 322).
// ---------------------------------------------------------------------------
#define PREP_W_BLOCKS 320
#define PREP_Z_BLOCKS 3
__global__ __launch_bounds__(256) void prep(
    const float* __restrict__ w_proj,
    const float* __restrict__ w_self1, const float* __restrict__ w_neigh1,
    const float* __restrict__ w_self2, const float* __restrict__ w_neigh2,
    ushort_t* __restrict__ wtp, ushort_t* __restrict__ wt1,
    ushort_t* __restrict__ wt2, int* __restrict__ bcnt,
    ushort_t* __restrict__ h1pad, ushort_t* __restrict__ h2pad)
{
    const int bid = blockIdx.x;
    const int tid = threadIdx.x;
    if (bid < PREP_W_BLOCKS) {
        int which = bid >> 6;                 // 0..4
        int t = (bid & 63) * 256 + tid;       // 0..16383
        int n = t >> 7, k = t & 127;
        float v;
        ushort_t* d;
        switch (which) {
            case 0: v = w_proj  [(size_t)k * 128 + n]; d = wtp + (size_t)n * 128 + k;       break;
            case 1: v = w_self1 [(size_t)k * 128 + n]; d = wt1 + (size_t)n * 256 + k;       break;
            case 2: v = w_neigh1[(size_t)k * 128 + n]; d = wt1 + (size_t)n * 256 + 128 + k; break;
            case 3: v = w_self2 [(size_t)k * 128 + n]; d = wt2 + (size_t)n * 256 + k;       break;
            default:v = w_neigh2[(size_t)k * 128 + n]; d = wt2 + (size_t)n * 256 + 128 + k; break;
        }
        *d = f2bf(v);
    } else if (bid < PREP_W_BLOCKS + 2) {
        int i = (bid - PREP_W_BLOCKS) * 256 + tid;
        if (i < 2 * NB) bcnt[i] = 0;
    } else {
        uint_t* p1 = (uint_t*)h1pad;
        uint_t* p2 = (uint_t*)h2pad;
        if (tid < 64) p1[tid] = 0;
        else if (tid < 128) p2[tid - 64] = 0;
    }
}

// ---------------------------------------------------------------------------
// gemm0 (layer 0, CVT): h1 = relu(feat @ Wp + b). fp32 A reg-converted,
// W via gload_lds, single-buffer (r6-verified path).
// ---------------------------------------------------------------------------
__global__ __launch_bounds__(256, 4) void gemm0(
    const float* __restrict__ feat, const ushort_t* __restrict__ W,
    const float* __restrict__ bias, ushort_t* __restrict__ outp)
{
    __shared__ char smem[32768];
    ushort_t* At = (ushort_t*)smem;             // 128*32*2 = 8192 B
    ushort_t* Wt = (ushort_t*)(smem + 8192);    // 8192 B
    ushort_t* Ot = (ushort_t*)smem;             // epilogue: full 32 KB

    const int tid  = threadIdx.x;
    const int lane = tid & 63;
    const int wav  = tid >> 6;
    const int row0 = blockIdx.x * 128;
    const int m0   = (wav & 1) * 64;
    const int n0   = (wav >> 1) * 64;

    f32x4 acc[4][4];
#pragma unroll
    for (int i = 0; i < 4; ++i)
#pragma unroll
        for (int j = 0; j < 4; ++j) acc[i][j] = (f32x4){0.f, 0.f, 0.f, 0.f};

    const int cl = lane & 15;
    const int q  = lane >> 4;

#pragma unroll 1
    for (int ch = 0; ch < 4; ++ch) {
        const int kA = ch * 32;

        if (ch) __syncthreads();
#pragma unroll
        for (int j = 0; j < 2; ++j) {
            int cb = (j * 4 + wav) * 64;
            int c  = cb + lane;
            int r  = c >> 2, k2 = c & 3;
            gload16(W + (size_t)r * 128 + kA + k2 * 8, Wt + cb * 8);
        }
        uint4 av[2];
#pragma unroll
        for (int j = 0; j < 2; ++j) {
            int g = tid + 256 * j;
            int r = g >> 2;
            int c = (g & 3) * 8;
            int grow = row0 + r;
            if (grow >= NN) grow = NN - 1;
            float4 f0 = *(const float4*)(feat + (size_t)grow * DD + kA + c);
            float4 f1 = *(const float4*)(feat + (size_t)grow * DD + kA + c + 4);
            av[j].x = pack2bf(f0.x, f0.y);
            av[j].y = pack2bf(f0.z, f0.w);
            av[j].z = pack2bf(f1.x, f1.y);
            av[j].w = pack2bf(f1.z, f1.w);
        }
#pragma unroll
        for (int j = 0; j < 2; ++j) {
            int g = tid + 256 * j;
            int r = g >> 2;
            int c = (g & 3) * 8;
            *(uint4*)(&At[r * 32 + c]) = av[j];
        }
        __syncthreads();

        bf16x8 af[4], bfr[4];
#pragma unroll
        for (int i = 0; i < 4; ++i)
            af[i] = *(const bf16x8*)(&At[(m0 + i * 16 + cl) * 32 + q * 8]);
#pragma unroll
        for (int j = 0; j < 4; ++j)
            bfr[j] = *(const bf16x8*)(&Wt[(n0 + j * 16 + cl) * 32 + q * 8]);
#pragma unroll
        for (int i = 0; i < 4; ++i)
#pragma unroll
            for (int j = 0; j < 4; ++j)
                acc[i][j] = __builtin_amdgcn_mfma_f32_16x16x32_bf16(
                    af[i], bfr[j], acc[i][j], 0, 0, 0);
    }

    // Epilogue. C/D layout: col=lane&15, row=(lane>>4)*4+reg  [m89/m91]
    __syncthreads();
#pragma unroll
    for (int j = 0; j < 4; ++j) {
        int c = n0 + j * 16 + cl;
        float bv = bias[c];
#pragma unroll
        for (int i = 0; i < 4; ++i) {
#pragma unroll
            for (int reg = 0; reg < 4; ++reg) {
                int r = m0 + i * 16 + 4 * q + reg;
                float v = acc[i][j][reg] + bv;
                v = fmaxf(v, 0.f);
                Ot[r * 128 + c] = f2bf(v);
            }
        }
    }
    __syncthreads();
    int rows = NN - row0; if (rows > 128) rows = 128;
    for (int t = tid; t < rows * 16; t += 256) {
        int r = t >> 4, c8 = (t & 15) * 8;
        *(uint4*)(outp + (size_t)(row0 + r) * DD + c8) =
            *(const uint4*)(&Ot[r * 128 + c8]);
    }
}

// ---------------------------------------------------------------------------
// partA2: bin BOTH edge lists into 512-node buckets. 1024 threads/block
// (256->512 was +11 µs total, r12): more waves/CU at the SAME 196-block
// edge partition — bucket write runs (hence WRITE_SIZE) stay identical.
// ---------------------------------------------------------------------------
__global__ __launch_bounds__(1024) void partA2(
    const int* __restrict__ e0s, const int* __restrict__ e0d, int E0,
    const int* __restrict__ e1s, const int* __restrict__ e1d, int E1,
    int* __restrict__ bcnt, uint_t* __restrict__ pairs)
{
    __shared__ int hist[NB];
    __shared__ int base[NB];
    const int tid  = threadIdx.x;
    const int half = blockIdx.x >= PA_BLOCKS;
    const int* __restrict__ src = half ? e1s : e0s;
    const int* __restrict__ dst = half ? e1d : e0d;
    const int E = half ? E1 : E0;
    int* bc = bcnt + half * NB;
    uint_t* pp = pairs + (size_t)half * NB * CAPB;
    const int blk = blockIdx.x - half * PA_BLOCKS;
    const int chunk = (E + PA_BLOCKS - 1) / PA_BLOCKS;
    const int ea = blk * chunk;
    int eb = ea + chunk; if (eb > E) eb = E;

    for (int b = tid; b < NB; b += 1024) hist[b] = 0;
    __syncthreads();
    for (int e = ea + tid; e < eb; e += 1024)
        atomicAdd(&hist[dst[e] >> 9], 1);
    __syncthreads();
    for (int b = tid; b < NB; b += 1024) {
        base[b] = atomicAdd(&bc[b], hist[b]);
        hist[b] = 0;
    }
    __syncthreads();
    for (int e = ea + tid; e < eb; e += 1024) {
        int d = dst[e];
        int b = d >> 9;
        int off = atomicAdd(&hist[b], 1);
        int p = base[b] + off;
        if (p < CAPB)
            pp[(size_t)b * CAPB + p] =
                ((uint_t)(d & (NPB - 1)) << 17) | (uint_t)src[e];
    }
}

// ---------------------------------------------------------------------------
// partB: one block per bucket (392 blocks), 1024 threads/block (16 waves;
// 54 KB LDS -> 2 blocks/CU -> up to 32 waves/CU). Scan: first 512 threads
// own the 512 bins; ALL barriers unconditional (guarded bodies only).
// ---------------------------------------------------------------------------
__global__ __launch_bounds__(1024) void partB(
    uint_t* __restrict__ pairs, const int* __restrict__ bcnt,
    int* __restrict__ counts, int* __restrict__ offs)
{
    __shared__ int cnt[NPB];
    __shared__ int loff[NPB];
    __shared__ int ssc[NPB];
    __shared__ int image[CAPB];

    const int tid  = threadIdx.x;
    const int half = blockIdx.x >= NB;
    const int b    = blockIdx.x - half * NB;
    const int n0   = b << 9;
    int nb = NN - n0; if (nb > NPB) nb = NPB;
    int tot = bcnt[half * NB + b]; if (tot > CAPB) tot = CAPB;
    uint_t* pb = pairs + (size_t)(half * NB + b) * CAPB;
    const int gbase = (half * NB + b) * CAPB;
    int* cnts  = counts + (size_t)half * NN;
    int* offsl = offs   + (size_t)half * NN;

    if (tid < NPB) cnt[tid] = 0;
    __syncthreads();
    for (int i = tid; i < tot; i += 1024)
        atomicAdd(&cnt[pb[i] >> 17], 1);
    __syncthreads();

    // exclusive scan over 512 bins by the first 512 threads (Hillis-Steele);
    // barriers unconditional.
    int s = 0;
    if (tid < NPB) { s = cnt[tid]; ssc[tid] = s; }
    __syncthreads();
    for (int off = 1; off < NPB; off <<= 1) {
        int t = 0;
        if (tid < NPB && tid >= off) t = ssc[tid - off];
        __syncthreads();
        if (tid < NPB && tid >= off) ssc[tid] += t;
        __syncthreads();
    }
    if (tid < NPB) loff[tid] = ssc[tid] - s;
    __syncthreads();

    if (tid < nb) {
        cnts[n0 + tid]  = cnt[tid];
        offsl[n0 + tid] = gbase + loff[tid];
    }
    if (tid < NPB) cnt[tid] = 0;        // reuse as cursor
    __syncthreads();

    for (int i = tid; i < tot; i += 1024) {
        uint_t p = pb[i];
        int ln  = p >> 17;
        int pos = loff[ln] + atomicAdd(&cnt[ln], 1);
        image[pos] = (int)(p & 0x1FFFFu);
    }
    __syncthreads();
    for (int i = tid; i < tot; i += 1024) pb[i] = (uint_t)image[i];
}

// ---------------------------------------------------------------------------
// bf16 MFMA GEMM (layers 1/2): out = act( [A | Bm] @ W + bias ).
// 2-phase double-buffered gload_lds staging (r6-verified, ~22 µs).
// ---------------------------------------------------------------------------
template <bool RELU>
__global__ __launch_bounds__(256, 4) void gemm_bf16(
    const ushort_t* __restrict__ Av, const ushort_t* __restrict__ Bm,
    const ushort_t* __restrict__ W, const float* __restrict__ bias,
    ushort_t* __restrict__ outp)
{
    __shared__ char smem[32768];
    ushort_t* Ot = (ushort_t*)smem;             // epilogue: full 32 KB

    const int tid  = threadIdx.x;
    const int lane = tid & 63;
    const int wav  = tid >> 6;
    const int row0 = blockIdx.x * 128;
    const int m0   = (wav & 1) * 64;
    const int n0   = (wav >> 1) * 64;
    const int KTOT = 256;
    const int NCH  = 8;

    f32x4 acc[4][4];
#pragma unroll
    for (int i = 0; i < 4; ++i)
#pragma unroll
        for (int j = 0; j < 4; ++j) acc[i][j] = (f32x4){0.f, 0.f, 0.f, 0.f};

    const int cl = lane & 15;
    const int q  = lane >> 4;

    auto STAGE = [&](int ch, int buf) {
        const bool second = (ch >= 4);
        const int kA = (ch & 3) * 32;
        const int kW = ch * 32;
        ushort_t* At = (ushort_t*)(smem + buf * 16384);
        ushort_t* Wt = At + 4096;            // +8192 bytes
        const ushort_t* sp = second ? Bm : Av;
#pragma unroll
        for (int j = 0; j < 2; ++j) {
            int cb = (j * 4 + wav) * 64;
            int c  = cb + lane;
            int r  = c >> 2, k2 = c & 3;
            int grow = row0 + r;
            if (grow >= NN) grow = NN - 1;
            gload16(sp + (size_t)grow * DD + kA + k2 * 8, At + cb * 8);
            gload16(W + (size_t)r * KTOT + kW + k2 * 8, Wt + cb * 8);
        }
    };
    auto COMPUTE = [&](int buf) {
        ushort_t* At = (ushort_t*)(smem + buf * 16384);
        ushort_t* Wt = At + 4096;
        bf16x8 af[4], bfr[4];
#pragma unroll
        for (int i = 0; i < 4; ++i)
            af[i] = *(const bf16x8*)(&At[(m0 + i * 16 + cl) * 32 + q * 8]);
#pragma unroll
        for (int j = 0; j < 4; ++j)
            bfr[j] = *(const bf16x8*)(&Wt[(n0 + j * 16 + cl) * 32 + q * 8]);
#pragma unroll
        for (int i = 0; i < 4; ++i)
#pragma unroll
            for (int j = 0; j < 4; ++j)
                acc[i][j] = __builtin_amdgcn_mfma_f32_16x16x32_bf16(
                    af[i], bfr[j], acc[i][j], 0, 0, 0);
    };

    STAGE(0, 0);
    asm volatile("s_waitcnt vmcnt(0)" ::: "memory");
    __builtin_amdgcn_s_barrier();
    int cur = 0;
#pragma unroll 1
    for (int ch = 0; ch < NCH - 1; ++ch) {
        STAGE(ch + 1, cur ^ 1);   // issue next-chunk loads (other buffer)
        COMPUTE(cur);             // ds_read+MFMA current
        asm volatile("s_waitcnt vmcnt(0)" ::: "memory");
        __builtin_amdgcn_s_barrier();
        cur ^= 1;
    }
    COMPUTE(cur);                 // last chunk, no prefetch

    // Epilogue. C/D layout: col=lane&15, row=(lane>>4)*4+reg  [m89/m91]
    __syncthreads();
#pragma unroll
    for (int j = 0; j < 4; ++j) {
        int c = n0 + j * 16 + cl;
        float bv = bias[c];
#pragma unroll
        for (int i = 0; i < 4; ++i) {
#pragma unroll
            for (int reg = 0; reg < 4; ++reg) {
                int r = m0 + i * 16 + 4 * q + reg;
                float v = acc[i][j][reg] + bv;
                if constexpr (RELU) v = fmaxf(v, 0.f);
                Ot[r * 128 + c] = f2bf(v);
            }
        }
    }
    __syncthreads();
    int rows = NN - row0; if (rows > 128) rows = 128;
    for (int t = tid; t < rows * 16; t += 256) {
        int r = t >> 4, c8 = (t & 15) * 8;
        *(uint4*)(outp + (size_t)(row0 + r) * DD + c8) =
            *(const uint4*)(&Ot[r * 128 + c8]);
    }
}

// ---------------------------------------------------------------------------
// CSR mean-aggregate over bf16 h (best measured: 57.4-61 µs, FROZEN —
// at the chip global-load service ceiling (~6.7 TB/s delivered); r2-r4:
// MLP null, guards small win, TLP cut regression, r10 LDS-fusion regression).
// ---------------------------------------------------------------------------
#define AGG_ISSUE(V, J)                                                   \
    do {                                                                  \
        int s_[8];                                                        \
        _Pragma("unroll")                                                 \
        for (int u = 0; u < 8; ++u) {                                     \
            int jj = (J) + u;                                             \
            int jc = jj < cnt ? jj : cnt - 1;                             \
            int sv = (int)csr[start + jc];                                \
            s_[u] = jj < cnt ? sv : NN;                                   \
        }                                                                 \
        _Pragma("unroll")                                                 \
        for (int u = 0; u < 8; ++u)                                       \
            V[u] = *(const uint4*)(hl + (size_t)s_[u] * DD);              \
    } while (0)

#define AGG_ACCUM(V)                                                      \
    do {                                                                  \
        _Pragma("unroll")                                                 \
        for (int u = 0; u < 8; ++u) {                                     \
            a0 += bflo(V[u].x); a1 += bfhi(V[u].x);                       \
            a2 += bflo(V[u].y); a3 += bfhi(V[u].y);                       \
            a4 += bflo(V[u].z); a5 += bfhi(V[u].z);                       \
            a6 += bflo(V[u].w); a7 += bfhi(V[u].w);                       \
        }                                                                 \
    } while (0)

__global__ __launch_bounds__(256) void aggregate_bf16(
    const ushort_t* __restrict__ h, const uint_t* __restrict__ csr,
    const int* __restrict__ offs, const int* __restrict__ counts,
    ushort_t* __restrict__ mean, int nn)
{
    int gid  = blockIdx.x * 256 + threadIdx.x;
    int node = gid >> 4;
    if (node >= nn) return;
    int lane  = gid & 15;
    int start = offs[node];
    int cnt   = counts[node];
    const ushort_t* __restrict__ hl = h + lane * 8;

    float a0 = 0.f, a1 = 0.f, a2 = 0.f, a3 = 0.f;
    float a4 = 0.f, a5 = 0.f, a6 = 0.f, a7 = 0.f;

    int nbt = (cnt + 7) >> 3;        // number of (padded) 8-batches
    if (nbt > 0) {
        uint4 va[8], vb[8];
        AGG_ISSUE(va, 0);
        int j = 8, b = 1;
        for (; b + 1 < nbt; b += 2) {
            AGG_ISSUE(vb, j); j += 8;      // batch B in flight...
            AGG_ACCUM(va);                 // ...while A is consumed
            AGG_ISSUE(va, j); j += 8;
            AGG_ACCUM(vb);
        }
        if (b < nbt) {                     // one trailing issued batch
            AGG_ISSUE(vb, j);
            AGG_ACCUM(va);
            AGG_ACCUM(vb);
        } else {
            AGG_ACCUM(va);
        }
    }

    float rinv = 1.0f / (float)(cnt > 1 ? cnt : 1);
    uint4 o;
    o.x = pack2bf(a0 * rinv, a1 * rinv);
    o.y = pack2bf(a2 * rinv, a3 * rinv);
    o.z = pack2bf(a4 * rinv, a5 * rinv);
    o.w = pack2bf(a6 * rinv, a7 * rinv);
    *(uint4*)(mean + (size_t)node * DD + lane * 8) = o;
}

// ---------------------------------------------------------------------------
// Fused edge scoring on bf16 h3 (same gather service ceiling, FROZEN).
// ---------------------------------------------------------------------------
__device__ __forceinline__ float dot8(uint4 a, uint4 b) {
    return bflo(a.x) * bflo(b.x) + bfhi(a.x) * bfhi(b.x)
         + bflo(a.y) * bflo(b.y) + bfhi(a.y) * bfhi(b.y)
         + bflo(a.z) * bflo(b.z) + bfhi(a.z) * bfhi(b.z)
         + bflo(a.w) * bflo(b.w) + bfhi(a.w) * bfhi(b.w);
}

__global__ __launch_bounds__(256) void score_both(
    const ushort_t* __restrict__ h,
    const int* __restrict__ ps, const int* __restrict__ pd,
    const int* __restrict__ ns, const int* __restrict__ nd,
    float* __restrict__ out, int EP, int TE)
{
    int gid = blockIdx.x * 256 + threadIdx.x;
    int grp = gid >> 4;
    int e0 = grp * 2;
    if (e0 >= TE) return;
    int lane = gid & 15;
    int e1 = e0 + 1;
    bool has1 = (e1 < TE);
    int ee = has1 ? e1 : e0;

    int s0, d0, s1, d1;
    if (e0 < EP) { s0 = ps[e0]; d0 = pd[e0]; }
    else         { s0 = ns[e0 - EP]; d0 = nd[e0 - EP]; }
    if (ee < EP) { s1 = ps[ee]; d1 = pd[ee]; }
    else         { s1 = ns[ee - EP]; d1 = nd[ee - EP]; }

    const ushort_t* __restrict__ hl = h + lane * 8;
    uint4 va0 = *(const uint4*)(hl + (size_t)s0 * DD);
    uint4 vb0 = *(const uint4*)(hl + (size_t)d0 * DD);
    uint4 va1 = *(const uint4*)(hl + (size_t)s1 * DD);
    uint4 vb1 = *(const uint4*)(hl + (size_t)d1 * DD);

    float r0 = dot8(va0, vb0);
    float r1 = dot8(va1, vb1);
#pragma unroll
    for (int off = 8; off; off >>= 1) {
        r0 += __shfl_down(r0, off, 16);
        r1 += __shfl_down(r1, off, 16);
    }
    if (lane == 0) {
        out[e0] = r0;
        if (has1) out[e1] = r1;
    }
}

// ---------------------------------------------------------------------------

extern "C" void kernel_launch(void* const* d_in, const int* in_sizes, int n_in,
                              void* d_out, int out_size, void* d_ws, size_t ws_size,
                              hipStream_t stream)
{
    const float* feat    = (const float*)d_in[0];
    const int*   e0s     = (const int*)d_in[1];
    const int*   e0d     = (const int*)d_in[2];
    const int*   e1s     = (const int*)d_in[3];
    const int*   e1d     = (const int*)d_in[4];
    const int*   ps      = (const int*)d_in[5];
    const int*   pd      = (const int*)d_in[6];
    const int*   ns      = (const int*)d_in[7];
    const int*   nd      = (const int*)d_in[8];
    const float* w_proj  = (const float*)d_in[9];
    const float* b_proj  = (const float*)d_in[10];
    const float* w_self1 = (const float*)d_in[11];
    const float* w_neigh1= (const float*)d_in[12];
    const float* b1      = (const float*)d_in[13];
    const float* w_self2 = (const float*)d_in[14];
    const float* w_neigh2= (const float*)d_in[15];
    const float* b2      = (const float*)d_in[16];

    float* out = (float*)d_out;

    const size_t NF  = (size_t)NN * DD;
    const size_t NFP = NF + DD;          // +1 pad row (index NN, zeroed)
    char* base = (char*)d_ws;

    // bf16 buffers, NFP*2 bytes each (pad row NN for unguarded aggregate).
    ushort_t* h3   = (ushort_t*)base;
    ushort_t* h1   = h3 + NFP;
    ushort_t* mean = h1 + NFP;
    ushort_t* h2   = mean + NFP;

    uint_t* pairs  = (uint_t*)(h2 + NFP);                // 2*NB*CAPB*4 = 19.3 MB
    int*    bcnt   = (int*)(pairs + (size_t)2 * NB * CAPB);   // [2*NB]
    int*    counts = bcnt + 2 * NB;                      // [2*NN]
    int*    offs   = counts + 2 * NN;                    // [2*NN]
    ushort_t* wts  = (ushort_t*)(offs + 2 * NN);
    ushort_t* wtp = wts;                 // [128][128]
    ushort_t* wt1 = wts + 128 * 128;     // [128][256]
    ushort_t* wt2 = wt1 + 128 * 256;     // [128][256]

    const int E0 = in_sizes[1];
    const int E1 = in_sizes[3];
    const int EP = in_sizes[5];
    const int EN = in_sizes[7];

    const int AGB = (NN * 16 + 255) / 256;

    // ---- Prep: weight transposes + bcnt zero + pad-row zero
    prep<<<PREP_W_BLOCKS + PREP_Z_BLOCKS, 256, 0, stream>>>(
        w_proj, w_self1, w_neigh1, w_self2, w_neigh2, wtp, wt1, wt2, bcnt,
        h1 + NF, h2 + NF);

    // ---- Build both CSRs (196-block partition, 1024-thread blocks)
    partA2<<<2 * PA_BLOCKS, 1024, 0, stream>>>(
        e0s, e0d, E0, e1s, e1d, E1, bcnt, pairs);
    partB<<<2 * NB, 1024, 0, stream>>>(pairs, bcnt, counts, offs);

    // ---- Layer 0: h1 = relu(feat @ w_proj + b_proj)
    gemm0<<<GBLK, 256, 0, stream>>>(feat, wtp, b_proj, h1);

    // ---- Layer 1: mean over edge0, then dual GEMM
    aggregate_bf16<<<AGB, 256, 0, stream>>>(h1, pairs, offs, counts, mean, NN);
    gemm_bf16<true><<<GBLK, 256, 0, stream>>>(h1, mean, wt1, b1, h2);

    // ---- Layer 2: mean over edge1, then dual GEMM
    aggregate_bf16<<<AGB, 256, 0, stream>>>(
        h2, pairs, offs + NN, counts + NN, mean, NN);
    gemm_bf16<false><<<GBLK, 256, 0, stream>>>(h2, mean, wt2, b2, h3);

    // ---- Fused scoring on bf16 h3
    const int TE = EP + EN;
    const int NG = (TE + 1) / 2;
    score_both<<<(NG * 16 + 255) / 256, 256, 0, stream>>>(
        h3, ps, pd, ns, nd, out, EP, TE);
}